// Round 1
// baseline (11829.343 us; speedup 1.0000x reference)
//
#include <hip/hip_runtime.h>
#include <math.h>

// ---------------------------------------------------------------------------
// DisableGateLSTM: 512-step LSTM over 64 independent chains.
// 256 blocks x 512 threads, 1 block/CU (LDS ~152KB forces it -> all blocks
// co-resident, plain launch is deadlock-safe for the group barrier).
// 4 groups x 64 blocks; group g owns chains [16g,16g+16); block j-in-group
// owns hidden units [8j, 8j+8) = 32 gate rows (f,i,o,g x 8). Weights for
// those rows live in LDS for the whole kernel (no per-step weight traffic).
// ---------------------------------------------------------------------------

#define BATCH   64
#define SEQ     512
#define EMBED   256
#define HIDDEN  512
#define GD      768          // EMBED + HIDDEN (concat: [h, x])
#define CLASSES 4

#define NBLK    256
#define NTHR    512
#define GROUPS  4
#define GB      64           // blocks per group
#define CPG     16           // chains per group
#define UPB     8            // hidden units per block
#define ROWS    32           // 4 gates * UPB

#define WH_PAD  516          // 512 + 4 (keeps 16B alignment, breaks some pow2 strides)
#define WX_PAD  260          // 256 + 4

__device__ __forceinline__ void groupBarrier(unsigned* cnt, unsigned* gen,
                                             unsigned target) {
  __syncthreads();                       // all block's LDS+global work issued
  if (threadIdx.x == 0) {
    __threadfence();                     // publish h/max stores (agent scope)
    unsigned old = __hip_atomic_fetch_add(cnt, 1u, __ATOMIC_ACQ_REL,
                                          __HIP_MEMORY_SCOPE_AGENT);
    if (old == GB - 1u) {
      __hip_atomic_store(cnt, 0u, __ATOMIC_RELAXED, __HIP_MEMORY_SCOPE_AGENT);
      __hip_atomic_fetch_add(gen, 1u, __ATOMIC_RELEASE,
                             __HIP_MEMORY_SCOPE_AGENT);
    } else {
      unsigned v;
      do {
        __builtin_amdgcn_s_sleep(1);
        v = __hip_atomic_load(gen, __ATOMIC_ACQUIRE, __HIP_MEMORY_SCOPE_AGENT);
      } while (v < target);
    }
  }
  __syncthreads();
}

__global__ __launch_bounds__(NTHR, 1) void lstm_persistent(
    const int*   __restrict__ ids,   // [64][512]
    const float* __restrict__ emb,   // [32000][256]
    const float* __restrict__ Wf, const float* __restrict__ bf,
    const float* __restrict__ Wi, const float* __restrict__ bi,
    const float* __restrict__ Wo, const float* __restrict__ bo,
    const float* __restrict__ Wc, const float* __restrict__ bc,
    const float* __restrict__ fcw,   // [4][512]
    const float* __restrict__ fcb,   // [4]
    float* __restrict__ out,         // [64][4]
    float* __restrict__ ws)
{
  __shared__ __align__(16) float sWh[ROWS][WH_PAD];   // 66,048 B
  __shared__ __align__(16) float sWx[ROWS][WX_PAD];   // 33,280 B
  __shared__ __align__(16) float sH [CPG][WH_PAD];    // 33,024 B (reused as reduce scratch)
  __shared__ __align__(16) float sX [CPG][WX_PAD];    // 16,640 B
  __shared__ float sG[ROWS][CPG];                     //  2,048 B
  __shared__ float sC[UPB][CPG];
  __shared__ float sM[UPB][CPG];
  __shared__ float sB[ROWS];

  const int tid = threadIdx.x;
  const int bid = blockIdx.x;
  const int g   = bid & 3;        // group 0..3  (blocks of a group spread 2 XCDs)
  const int j   = bid >> 2;       // in-group rank 0..63
  const int u0  = j * UPB;        // first hidden unit owned by this block

  float*    hbuf    = ws;                                  // [2][64][512]
  float*    wmax    = ws + 2 * BATCH * HIDDEN;             // [64][512]
  unsigned* barArea = (unsigned*)(ws + 3 * BATCH * HIDDEN);
  unsigned* cnt     = barArea + g * 64;                    // 256B apart per group
  unsigned* gen     = barArea + GROUPS * 64 + g * 64;

  // ---- load this block's weight rows into LDS (once) ----
  for (int r = 0; r < ROWS; ++r) {
    const float* W = (r < 8) ? Wf : (r < 16) ? Wi : (r < 24) ? Wo : Wc;
    const float* src = W + (size_t)(u0 + (r & 7)) * GD;
    for (int col = tid; col < GD; col += NTHR) {
      float v = src[col];
      if (col < HIDDEN) sWh[r][col] = v;
      else              sWx[r][col - HIDDEN] = v;
    }
  }
  if (tid < ROWS) {
    const float* bv = (tid < 8) ? bf : (tid < 16) ? bi : (tid < 24) ? bo : bc;
    sB[tid] = bv[u0 + (tid & 7)];
  }
  if (tid < UPB * CPG) {
    ((float*)sC)[tid] = 0.0f;
    ((float*)sM)[tid] = -3.402823e38f;
  }
  __syncthreads();

  // thread tiling for the 32x16 (rows x chains) fragment, K split 16 ways
  const int cg = tid & 3;          // chain group: chains [4cg,4cg+4)
  const int rg = (tid >> 2) & 7;   // row group:   rows   [4rg,4rg+4)
  const int ks = tid >> 5;         // k-split 0..15

  const int stg_c = tid >> 5;      // staging: chain 0..15
  const int stg_s = tid & 31;      // staging: lane-in-chain

  unsigned target = 0;

  for (int t = 0; t < SEQ; ++t) {
    // ---- stage h_prev[16][512] and x_t[16][256] into LDS ----
    {
      const float* hsrc = hbuf + (size_t)(t & 1) * BATCH * HIDDEN
                               + (size_t)(g * CPG + stg_c) * HIDDEN;
      #pragma unroll
      for (int kk = 0; kk < 16; ++kk) {
        int k = kk * 32 + stg_s;
        sH[stg_c][k] = hsrc[k];
      }
      int id = ids[(g * CPG + stg_c) * SEQ + t];
      const float* xsrc = emb + (size_t)id * EMBED;
      #pragma unroll
      for (int ee = 0; ee < 8; ++ee) {
        int e = ee * 32 + stg_s;
        sX[stg_c][e] = xsrc[e];
      }
    }
    __syncthreads();

    // ---- fragment GEMM: acc[4 rows][4 chains] over this thread's k slice ----
    float acc[4][4];
    #pragma unroll
    for (int ri = 0; ri < 4; ++ri)
      #pragma unroll
      for (int ci = 0; ci < 4; ++ci) acc[ri][ci] = 0.0f;

    {
      const int k0 = ks * 32;
      #pragma unroll 2
      for (int k = k0; k < k0 + 32; k += 4) {
        float4 hv[4], wv[4];
        #pragma unroll
        for (int ci = 0; ci < 4; ++ci)
          hv[ci] = *(const float4*)&sH[cg * 4 + ci][k];
        #pragma unroll
        for (int ri = 0; ri < 4; ++ri)
          wv[ri] = *(const float4*)&sWh[rg * 4 + ri][k];
        #pragma unroll
        for (int ri = 0; ri < 4; ++ri)
          #pragma unroll
          for (int ci = 0; ci < 4; ++ci) {
            acc[ri][ci] = fmaf(wv[ri].x, hv[ci].x, acc[ri][ci]);
            acc[ri][ci] = fmaf(wv[ri].y, hv[ci].y, acc[ri][ci]);
            acc[ri][ci] = fmaf(wv[ri].z, hv[ci].z, acc[ri][ci]);
            acc[ri][ci] = fmaf(wv[ri].w, hv[ci].w, acc[ri][ci]);
          }
      }
      const int e0 = ks * 16;
      #pragma unroll 2
      for (int e = e0; e < e0 + 16; e += 4) {
        float4 xv[4], wv[4];
        #pragma unroll
        for (int ci = 0; ci < 4; ++ci)
          xv[ci] = *(const float4*)&sX[cg * 4 + ci][e];
        #pragma unroll
        for (int ri = 0; ri < 4; ++ri)
          wv[ri] = *(const float4*)&sWx[rg * 4 + ri][e];
        #pragma unroll
        for (int ri = 0; ri < 4; ++ri)
          #pragma unroll
          for (int ci = 0; ci < 4; ++ci) {
            acc[ri][ci] = fmaf(wv[ri].x, xv[ci].x, acc[ri][ci]);
            acc[ri][ci] = fmaf(wv[ri].y, xv[ci].y, acc[ri][ci]);
            acc[ri][ci] = fmaf(wv[ri].z, xv[ci].z, acc[ri][ci]);
            acc[ri][ci] = fmaf(wv[ri].w, xv[ci].w, acc[ri][ci]);
          }
      }
    }
    __syncthreads();              // everyone done reading sH before we alias it

    // ---- k-split reduction via LDS (reuse sH as scratch: 8192 floats) ----
    float* red = &sH[0][0];
    #pragma unroll
    for (int ri = 0; ri < 4; ++ri)
      #pragma unroll
      for (int ci = 0; ci < 4; ++ci)
        red[((ks * 8 + rg) * 4 + cg) * 16 + ri * 4 + ci] = acc[ri][ci];
    __syncthreads();

    {
      int row = tid >> 4, ch = tid & 15;          // 512 threads = 32x16 pairs
      int rg2 = row >> 2, ri2 = row & 3, cg2 = ch >> 2, ci2 = ch & 3;
      float s = sB[row];
      #pragma unroll
      for (int q = 0; q < 16; ++q)
        s += red[((q * 8 + rg2) * 4 + cg2) * 16 + ri2 * 4 + ci2];
      sG[row][ch] = s;
    }
    __syncthreads();

    // ---- gate nonlinearities + state update (128 threads) ----
    if (tid < UPB * CPG) {
      int uu = tid & 7, ch = tid >> 3;
      float pf = sG[uu][ch];
      float pi = sG[8 + uu][ch];
      float po = sG[16 + uu][ch];
      float pg = sG[24 + uu][ch];
      float f  = 1.0f / (1.0f + expf(-pf));
      float i_ = 1.0f / (1.0f + expf(-pi));
      float o  = 1.0f / (1.0f + expf(-po));
      float gg = tanhf(pg);
      float cn = f * sC[uu][ch] + i_ * gg;
      float h  = o * tanhf(cn);
      sC[uu][ch] = cn;
      sM[uu][ch] = fmaxf(sM[uu][ch], h);
      hbuf[(size_t)((t + 1) & 1) * BATCH * HIDDEN
           + (size_t)(g * CPG + ch) * HIDDEN + (u0 + uu)] = h;
    }

    ++target;
    groupBarrier(cnt, gen, target);
  }

  // ---- publish running max, then head GEMV on group-leader blocks ----
  if (tid < UPB * CPG) {
    int uu = tid & 7, ch = tid >> 3;
    wmax[(size_t)(g * CPG + ch) * HIDDEN + (u0 + uu)] = sM[uu][ch];
  }
  ++target;
  groupBarrier(cnt, gen, target);

  if (j == 0) {
    // logits[b][cls] = fc_b[cls] + sum_u wmax[b][u] * fcw[cls][u]
    int ch  = tid & 15;
    int cls = (tid >> 4) & 3;
    int us  = tid >> 6;           // 0..7, 64 units each
    const float* mrow = wmax + (size_t)(g * CPG + ch) * HIDDEN;
    const float* wrow = fcw + (size_t)cls * HIDDEN;
    float s = 0.0f;
    for (int u = us * 64; u < us * 64 + 64; ++u)
      s = fmaf(mrow[u], wrow[u], s);
    float* red2 = &sG[0][0];      // 512 floats, layout us*64 + cls*16 + ch = tid
    red2[tid] = s;
    __syncthreads();
    if (tid < 64) {
      float tot = fcb[cls];
      #pragma unroll
      for (int q = 0; q < 8; ++q) tot += red2[q * 64 + tid];
      out[(g * CPG + ch) * CLASSES + cls] = tot;
    }
  }
}

extern "C" void kernel_launch(void* const* d_in, const int* in_sizes, int n_in,
                              void* d_out, int out_size, void* d_ws, size_t ws_size,
                              hipStream_t stream) {
  const int*   ids = (const int*)  d_in[0];
  const float* emb = (const float*)d_in[1];
  const float* Wf  = (const float*)d_in[2];
  const float* bf  = (const float*)d_in[3];
  const float* Wi  = (const float*)d_in[4];
  const float* bi  = (const float*)d_in[5];
  const float* Wo  = (const float*)d_in[6];
  const float* bo  = (const float*)d_in[7];
  const float* Wc  = (const float*)d_in[8];
  const float* bc  = (const float*)d_in[9];
  const float* fcw = (const float*)d_in[10];
  const float* fcb = (const float*)d_in[11];
  float* out = (float*)d_out;
  float* ws  = (float*)d_ws;

  // zero h0 (hbuf[0]) and the barrier area (ws is poisoned 0xAA each launch)
  hipMemsetAsync(d_ws, 0, (size_t)BATCH * HIDDEN * sizeof(float), stream);
  hipMemsetAsync((char*)d_ws + (size_t)3 * BATCH * HIDDEN * sizeof(float),
                 0, 4096, stream);

  lstm_persistent<<<dim3(NBLK), dim3(NTHR), 0, stream>>>(
      ids, emb, Wf, bf, Wi, bi, Wo, bo, Wc, bc, fcw, fcb, out, ws);
}

// Round 4
// 4510.987 us; speedup vs baseline: 2.6223x; 2.6223x over previous
//
#include <hip/hip_runtime.h>
#include <math.h>

// ---------------------------------------------------------------------------
// DisableGateLSTM: 512-step LSTM over 64 independent chains.
// 256 blocks x 512 threads, 1 block/CU (LDS ~155KB). 4 groups x 64 blocks;
// group g owns chains [16g,16g+16); block j-in-group owns hidden units
// [8j,8j+8) = 32 gate rows. Weights LDS-resident for the whole kernel.
// Cross-block h exchange: relaxed agent-scope atomics; NO acquire/release
// cache maintenance in the loop (R1's acquire-poll was the 11.8ms stall).
// R3 lesson: the sH "+16" column swizzle was NON-INJECTIVE (k and k+16
// collided for k%64 in [48,63]) -> 25% of h corrupted deterministically.
// Removed: the unswizzled pattern is only 2-way bank aliasing (free, m136).
// Gates use exact libm expf/tanhf (R1 numerics, absmax 0.0).
// ---------------------------------------------------------------------------

#define BATCH   64
#define SEQ     512
#define EMBED   256
#define HIDDEN  512
#define GD      768
#define CLASSES 4

#define NBLK    256
#define NTHR    512
#define GROUPS  4
#define GB      64
#define CPG     16
#define UPB     8
#define ROWS    32

// LDS strides (floats), with per-row 16B skews for the weight arrays
// (spreads 8 rg-rows across all 8 bank-quads; verified conflict-free).
#define SWHS 532
#define SWXS 276
#define SHS  544
#define SXS  268

typedef unsigned long long __attribute__((may_alias)) ull_a;

union F2U { float f[2]; unsigned long long u; };

__global__ __launch_bounds__(NTHR, 1) void lstm_persistent(
    const int*   __restrict__ ids,
    const float* __restrict__ emb,
    const float* __restrict__ Wf, const float* __restrict__ bf,
    const float* __restrict__ Wi, const float* __restrict__ bi,
    const float* __restrict__ Wo, const float* __restrict__ bo,
    const float* __restrict__ Wc, const float* __restrict__ bc,
    const float* __restrict__ fcw,
    const float* __restrict__ fcb,
    float* __restrict__ out,
    float* __restrict__ ws)
{
  __shared__ __align__(16) float sWh[ROWS * SWHS];
  __shared__ __align__(16) float sWx[ROWS * SWXS];
  __shared__ __align__(16) float sH [CPG * SHS];     // also 512*17 reduce scratch
  __shared__ __align__(16) float sX [CPG * SXS];
  __shared__ float sG[ROWS][CPG];
  __shared__ float sC[UPB][CPG];
  __shared__ float sM[UPB][CPG];
  __shared__ float sB[ROWS];

  const int tid = threadIdx.x;
  const int bid = blockIdx.x;
  const int g   = bid & 3;
  const int j   = bid >> 2;
  const int u0  = j * UPB;

  ull_a*    hbufU   = (ull_a*)ws;                            // [2][64][256] ull
  ull_a*    wmaxU   = hbufU + (size_t)BATCH * HIDDEN;        // [64][256] ull
  unsigned* barArea = (unsigned*)(ws + (size_t)3 * BATCH * HIDDEN);
  unsigned* cnt     = barArea + g * 64;
  unsigned* gen     = barArea + 256 + g * 64;

  // ---- weights -> LDS (skewed layout), once ----
  for (int r = 0; r < ROWS; ++r) {
    const float* W = (r < 8) ? Wf : (r < 16) ? Wi : (r < 24) ? Wo : Wc;
    const float* src = W + (size_t)(u0 + (r & 7)) * GD;
    const int skw = ((r >> 3) & 3) * 4;
    float* dh = sWh + r * SWHS + skw;
    float* dx = sWx + r * SWXS + skw;
    for (int col = tid; col < GD; col += NTHR) {
      float v = src[col];
      if (col < HIDDEN) dh[col] = v;
      else              dx[col - HIDDEN] = v;
    }
  }
  if (tid < ROWS) {
    const float* bv = (tid < 8) ? bf : (tid < 16) ? bi : (tid < 24) ? bo : bc;
    sB[tid] = bv[u0 + (tid & 7)];
  }
  if (tid < UPB * CPG) {
    ((float*)sC)[tid] = 0.0f;
    ((float*)sM)[tid] = -3.402823e38f;
  }

  // GEMM thread tiling: acc[4 rows][4 chains], K split 16 ways
  const int cg = tid & 3;
  const int rg = (tid >> 2) & 7;
  const int ks = tid >> 5;

  const int stg_c = tid >> 5;      // staging chain 0..15
  const int stg_s = tid & 31;      // staging lane
  const int bStg  = g * CPG + stg_c;

  const float* pH0  = sH  + (cg * 4) * SHS  + cg * 4;          // no k-swizzle
  const float* pX0  = sX  + (cg * 4) * SXS  + cg * 4;
  const float* pW0  = sWh + (rg * 4) * SWHS + ((rg >> 1) & 3) * 4;
  const float* pWx0 = sWx + (rg * 4) * SWXS + ((rg >> 1) & 3) * 4;

  // prefetch x_0 into registers
  float4 rx0, rx1;
  {
    int id0 = ids[(size_t)bStg * SEQ];
    const float4* xs = (const float4*)(emb + (size_t)id0 * EMBED);
    rx0 = xs[stg_s * 2];
    rx1 = xs[stg_s * 2 + 1];
  }

  for (int t = 0; t < SEQ; ++t) {
    const int pb = t & 1;

    // ---- wait for h_t (relaxed poll; no cache maintenance) ----
    if (tid == 0) {
      while (__hip_atomic_load(gen, __ATOMIC_RELAXED, __HIP_MEMORY_SCOPE_AGENT)
             < (unsigned)t)
        __builtin_amdgcn_s_sleep(1);
    }
    __atomic_signal_fence(__ATOMIC_ACQUIRE);
    __syncthreads();

    // ---- write prefetched x_t into sX; stage h_t via coherent loads ----
    {
      float* dx = sX + stg_c * SXS + ((stg_c >> 2) & 3) * 4 + stg_s * 8;
      *(float4*)dx = rx0;
      *(float4*)(dx + 4) = rx1;
    }
    {
      const ull_a* hs = hbufU + ((size_t)pb * BATCH + bStg) * (HIDDEN / 2);
      float* dh = sH + stg_c * SHS + ((stg_c >> 2) & 3) * 4;   // no k-swizzle
      #pragma unroll
      for (int kk = 0; kk < 8; ++kk) {
        unsigned long long v = __hip_atomic_load(hs + stg_s + kk * 32,
                                                 __ATOMIC_RELAXED,
                                                 __HIP_MEMORY_SCOPE_AGENT);
        *(ull_a*)(dh + 2 * stg_s + 64 * kk) = v;
      }
    }
    __syncthreads();

    // ---- GEMM fragment: 4 rows x 4 chains over this thread's k slice ----
    float acc[4][4];
    #pragma unroll
    for (int a = 0; a < 4; ++a)
      #pragma unroll
      for (int b2 = 0; b2 < 4; ++b2) acc[a][b2] = 0.0f;

    {
      const float* ph = pH0 + ks * 32;
      const float* pw = pW0 + ks * 32;
      #pragma unroll
      for (int kk = 0; kk < 8; ++kk) {
        float4 hv[4], wv[4];
        #pragma unroll
        for (int ci = 0; ci < 4; ++ci)
          hv[ci] = *(const float4*)(ph + ci * SHS + kk * 4);
        #pragma unroll
        for (int ri = 0; ri < 4; ++ri)
          wv[ri] = *(const float4*)(pw + ri * SWHS + kk * 4);
        #pragma unroll
        for (int ri = 0; ri < 4; ++ri)
          #pragma unroll
          for (int ci = 0; ci < 4; ++ci) {
            acc[ri][ci] = fmaf(wv[ri].x, hv[ci].x, acc[ri][ci]);
            acc[ri][ci] = fmaf(wv[ri].y, hv[ci].y, acc[ri][ci]);
            acc[ri][ci] = fmaf(wv[ri].z, hv[ci].z, acc[ri][ci]);
            acc[ri][ci] = fmaf(wv[ri].w, hv[ci].w, acc[ri][ci]);
          }
      }
      const float* px  = pX0 + ks * 16;
      const float* pwx = pWx0 + ks * 16;
      #pragma unroll
      for (int kk = 0; kk < 4; ++kk) {
        float4 xv[4], wv[4];
        #pragma unroll
        for (int ci = 0; ci < 4; ++ci)
          xv[ci] = *(const float4*)(px + ci * SXS + kk * 4);
        #pragma unroll
        for (int ri = 0; ri < 4; ++ri)
          wv[ri] = *(const float4*)(pwx + ri * SWXS + kk * 4);
        #pragma unroll
        for (int ri = 0; ri < 4; ++ri)
          #pragma unroll
          for (int ci = 0; ci < 4; ++ci) {
            acc[ri][ci] = fmaf(wv[ri].x, xv[ci].x, acc[ri][ci]);
            acc[ri][ci] = fmaf(wv[ri].y, xv[ci].y, acc[ri][ci]);
            acc[ri][ci] = fmaf(wv[ri].z, xv[ci].z, acc[ri][ci]);
            acc[ri][ci] = fmaf(wv[ri].w, xv[ci].w, acc[ri][ci]);
          }
      }
    }
    __syncthreads();                 // done reading sH; reuse as reduce scratch

    // ---- k-split reduction (stride-17 scratch) ----
    float* red = sH;
    {
      const int rank = ks * 32 + rg * 4 + cg;
      #pragma unroll
      for (int ri = 0; ri < 4; ++ri)
        #pragma unroll
        for (int ci = 0; ci < 4; ++ci)
          red[rank * 17 + ri * 4 + ci] = acc[ri][ci];
    }
    __syncthreads();
    {
      const int row = tid >> 4, ch = tid & 15;
      const int rg2 = row >> 2, ri2 = row & 3, cg2 = ch >> 2, ci2 = ch & 3;
      float s = sB[row];
      #pragma unroll
      for (int q = 0; q < 16; ++q)
        s += red[(q * 32 + rg2 * 4 + cg2) * 17 + ri2 * 4 + ci2];
      sG[row][ch] = s;
    }
    __syncthreads();

    // ---- prefetch x_{t+1} into registers (hides LLC latency) ----
    {
      const int tn = (t + 1 < SEQ) ? t + 1 : SEQ - 1;
      int idn = ids[(size_t)bStg * SEQ + tn];
      const float4* xs = (const float4*)(emb + (size_t)idn * EMBED);
      rx0 = xs[stg_s * 2];
      rx1 = xs[stg_s * 2 + 1];
    }

    // ---- gates + state update + coherent h store (EXACT libm math) ----
    if (tid < 64) {
      const int ch = tid >> 2, p = tid & 3;
      F2U pv;
      #pragma unroll
      for (int q = 0; q < 2; ++q) {
        const int uu = p * 2 + q;
        float pf = sG[uu][ch];
        float pi = sG[8 + uu][ch];
        float po = sG[16 + uu][ch];
        float pg = sG[24 + uu][ch];
        float f  = 1.0f / (1.0f + expf(-pf));
        float i_ = 1.0f / (1.0f + expf(-pi));
        float o  = 1.0f / (1.0f + expf(-po));
        float gg = tanhf(pg);
        float cn = f * sC[uu][ch] + i_ * gg;
        float h  = o * tanhf(cn);
        sC[uu][ch] = cn;
        sM[uu][ch] = fmaxf(sM[uu][ch], h);
        pv.f[q] = h;
      }
      __hip_atomic_store(
          hbufU + ((size_t)(pb ^ 1) * BATCH + g * CPG + ch) * (HIDDEN / 2)
                + (u0 >> 1) + p,
          pv.u, __ATOMIC_RELAXED, __HIP_MEMORY_SCOPE_AGENT);
    }
    __syncthreads();   // every wave drains vmcnt -> h stores coherence-visible

    // ---- arrival: monotonic count (never reset) ----
    if (tid == 0) {
      unsigned old = __hip_atomic_fetch_add(cnt, 1u, __ATOMIC_RELAXED,
                                            __HIP_MEMORY_SCOPE_AGENT);
      if (old == (unsigned)((t + 1) * GB - 1))
        __hip_atomic_store(gen, (unsigned)(t + 1), __ATOMIC_RELAXED,
                           __HIP_MEMORY_SCOPE_AGENT);
    }
  }

  // ---- publish running max (coherent), final barrier ----
  if (tid < 64) {
    const int ch = tid >> 2, p = tid & 3;
    F2U pv;
    pv.f[0] = sM[2 * p][ch];
    pv.f[1] = sM[2 * p + 1][ch];
    __hip_atomic_store(wmaxU + (size_t)(g * CPG + ch) * (HIDDEN / 2)
                              + (u0 >> 1) + p,
                       pv.u, __ATOMIC_RELAXED, __HIP_MEMORY_SCOPE_AGENT);
  }
  __syncthreads();
  if (tid == 0) {
    unsigned old = __hip_atomic_fetch_add(cnt, 1u, __ATOMIC_RELAXED,
                                          __HIP_MEMORY_SCOPE_AGENT);
    if (old == (unsigned)((SEQ + 1) * GB - 1))
      __hip_atomic_store(gen, (unsigned)(SEQ + 1), __ATOMIC_RELAXED,
                         __HIP_MEMORY_SCOPE_AGENT);
  }

  // ---- head GEMV on group-leader blocks ----
  if (j == 0) {
    if (tid == 0) {
      while (__hip_atomic_load(gen, __ATOMIC_RELAXED, __HIP_MEMORY_SCOPE_AGENT)
             < (unsigned)(SEQ + 1))
        __builtin_amdgcn_s_sleep(1);
    }
    __atomic_signal_fence(__ATOMIC_ACQUIRE);
    __syncthreads();

    const int ch = tid & 15, cls = (tid >> 4) & 3, us = tid >> 6;
    const ull_a* mrow = wmaxU + (size_t)(g * CPG + ch) * (HIDDEN / 2) + us * 32;
    const float* wrow = fcw + (size_t)cls * HIDDEN + us * 64;
    float s = 0.0f;
    for (int q = 0; q < 32; ++q) {
      F2U v;
      v.u = __hip_atomic_load(mrow + q, __ATOMIC_RELAXED,
                              __HIP_MEMORY_SCOPE_AGENT);
      s = fmaf(v.f[0], wrow[2 * q], s);
      s = fmaf(v.f[1], wrow[2 * q + 1], s);
    }
    float* red2 = &sG[0][0];
    red2[tid] = s;
    __syncthreads();
    if (tid < 64) {
      float tot = fcb[(tid >> 4) & 3];
      #pragma unroll
      for (int q = 0; q < 8; ++q) tot += red2[q * 64 + tid];
      out[(g * CPG + (tid & 15)) * CLASSES + ((tid >> 4) & 3)] = tot;
    }
  }
}

extern "C" void kernel_launch(void* const* d_in, const int* in_sizes, int n_in,
                              void* d_out, int out_size, void* d_ws, size_t ws_size,
                              hipStream_t stream) {
  const int*   ids = (const int*)  d_in[0];
  const float* emb = (const float*)d_in[1];
  const float* Wf  = (const float*)d_in[2];
  const float* bf  = (const float*)d_in[3];
  const float* Wi  = (const float*)d_in[4];
  const float* bi  = (const float*)d_in[5];
  const float* Wo  = (const float*)d_in[6];
  const float* bo  = (const float*)d_in[7];
  const float* Wc  = (const float*)d_in[8];
  const float* bc  = (const float*)d_in[9];
  const float* fcw = (const float*)d_in[10];
  const float* fcb = (const float*)d_in[11];

  // zero h0 (hbuf buffer 0) and the barrier counters
  hipMemsetAsync(d_ws, 0, (size_t)BATCH * HIDDEN * sizeof(float), stream);
  hipMemsetAsync((char*)d_ws + (size_t)3 * BATCH * HIDDEN * sizeof(float),
                 0, 4096, stream);

  lstm_persistent<<<dim3(NBLK), dim3(NTHR), 0, stream>>>(
      ids, emb, Wf, bf, Wi, bi, Wo, bo, Wc, bc, fcw, fcb,
      (float*)d_out, (float*)d_ws);
}